// Round 9
// baseline (5504.869 us; speedup 1.0000x reference)
//
#include <hip/hip_runtime.h>
#include <cstdint>
#include <cstddef>

#define BATCH  128
#define SEQT   512
#define EMB_D  300
#define VOCABN 5000
#define KP0    320
#define NU0    256
#define NU1    512
#define NU2    256
#define NDENSE 64
#define RING   16
#define LIM    (1 << 19)

typedef unsigned short ushortT;
typedef __attribute__((ext_vector_type(8))) short bf16x8;
typedef __attribute__((ext_vector_type(8))) unsigned short u16x8;
typedef __attribute__((ext_vector_type(4))) unsigned short u16x4;
typedef __attribute__((ext_vector_type(4))) float f32x4;

#define AGT __HIP_MEMORY_SCOPE_AGENT

static __device__ __forceinline__ unsigned short f2bf(float x) {
    union { float f; unsigned u; } v; v.f = x;
    const unsigned r = v.u + 0x7FFFu + ((v.u >> 16) & 1u);
    return (unsigned short)(r >> 16);
}
static __device__ __forceinline__ float bf2f(unsigned short b) {
    union { unsigned u; float f; } v; v.u = ((unsigned)b) << 16;
    return v.f;
}
static __device__ __forceinline__ float sigmoidf_(float x) {
    return 1.f / (1.f + __expf(-x));
}
static __device__ __forceinline__ unsigned ald(const unsigned* p) {
    return __hip_atomic_load((unsigned*)p, __ATOMIC_RELAXED, AGT);
}

// ---------------------------------------------------------------------------
// One-time converts
// ---------------------------------------------------------------------------
__global__ __launch_bounds__(256) void convert_WT(
    const float* __restrict__ W, ushortT* __restrict__ WbfT,
    int K, int NG, int KP, int total)
{
    for (int idx = blockIdx.x * 256 + threadIdx.x; idx < total; idx += gridDim.x * 256) {
        const int m = idx / KP, k = idx - m * KP;
        WbfT[idx] = (k < K) ? f2bf(W[(size_t)k * NG + m]) : (ushortT)0;
    }
}
__global__ __launch_bounds__(256) void convert_emb(
    const float* __restrict__ emb, ushortT* __restrict__ embbf)
{
    const int total = VOCABN * KP0;
    for (int idx = blockIdx.x * 256 + threadIdx.x; idx < total; idx += gridDim.x * 256) {
        const int v = idx / KP0, k = idx - v * KP0;
        embbf[idx] = (k < EMB_D) ? f2bf(emb[(size_t)v * EMB_D + k]) : (ushortT)0;
    }
}

// ---------------------------------------------------------------------------
// Precompute ALL of xg0 (no recurrence dep): xg0[t][g][m][b16] bf16,
// t full 0..511. 128Mx128N tile, BK=32, 4 waves, 16x16x32 bf16 MFMA.
// ---------------------------------------------------------------------------
__global__ __launch_bounds__(256) void gemm_xg0(
    const ushortT* __restrict__ embbf,   // [VOCAB][KP0]
    const int*   __restrict__ tokens,
    const ushortT* __restrict__ W0T,     // [1024][KP0]
    const float* __restrict__ bias,      // [1024]
    ushortT* __restrict__ xg0)           // [512][8][1024][16]
{
    __shared__ ushortT Wl[128][32];
    __shared__ ushortT Xl[128][32];
    __shared__ int tokL[128];

    const int tid = threadIdx.x;
    const int t   = blockIdx.x;
    const int m0  = blockIdx.y * 128;
    const int wv  = tid >> 6;
    const int lane = tid & 63;
    const int lo  = lane & 15;
    const int hi  = lane >> 4;

    if (tid < 128) tokL[tid] = tokens[tid * SEQT + t];
    __syncthreads();

    f32x4 acc[2][8];
    #pragma unroll
    for (int s = 0; s < 2; ++s)
        #pragma unroll
        for (int n = 0; n < 8; ++n)
            acc[s][n] = f32x4{0.f, 0.f, 0.f, 0.f};

    for (int k0 = 0; k0 < KP0; k0 += 32) {
        #pragma unroll
        for (int it = 0; it < 2; ++it) {
            const int idx = tid + it * 256;
            const int row = idx >> 2, gq = idx & 3;
            const int gs  = gq ^ ((row >> 1) & 3);
            *(u16x8*)&Wl[row][gs * 8] =
                *(const u16x8*)(W0T + (size_t)(m0 + row) * KP0 + k0 + gq * 8);
            *(u16x8*)&Xl[row][gs * 8] =
                *(const u16x8*)(embbf + (size_t)tokL[row] * KP0 + k0 + gq * 8);
        }
        __syncthreads();

        bf16x8 bfr[8];
        #pragma unroll
        for (int n = 0; n < 8; ++n) {
            const int row = n * 16 + lo;
            bfr[n] = *(const bf16x8*)&Xl[row][(hi ^ ((row >> 1) & 3)) * 8];
        }
        #pragma unroll
        for (int s = 0; s < 2; ++s) {
            const int row = wv * 32 + s * 16 + lo;
            const bf16x8 a = *(const bf16x8*)&Wl[row][(hi ^ ((row >> 1) & 3)) * 8];
            #pragma unroll
            for (int n = 0; n < 8; ++n)
                acc[s][n] = __builtin_amdgcn_mfma_f32_16x16x32_bf16(a, bfr[n], acc[s][n], 0, 0, 0);
        }
        __syncthreads();
    }

    #pragma unroll
    for (int s = 0; s < 2; ++s)
        #pragma unroll
        for (int j = 0; j < 4; ++j) {
            const int m = m0 + wv * 32 + s * 16 + hi * 4 + j;
            const float bi = bias[m];
            #pragma unroll
            for (int n = 0; n < 8; ++n)
                xg0[(((size_t)t * 8 + n) * 1024 + m) * 16 + lo] = f2bf(acc[s][n][j] + bi);
        }
}

// ---------------------------------------------------------------------------
// Recurrence role. Group grp = rid&7 (XCD-local) owns 16 batch rows; WG owns
// JCOLS h-cols x 4 gates (wave w: gate w&3, col-half w>>2). U cols persistent
// in bf16 B-frags. 2 flags/WG (one per c-wave, chh half); c-waves release
// after their OWN vmcnt drain (no trailing barrier). Polls strided over
// lanes: own-h flags >= t, xg flags >= t+1, ring-guard flags >= t-(RING-1).
// ---------------------------------------------------------------------------
template<int U_, int JCOLS>
__device__ void rec_role(
    int rid,
    const float* __restrict__ Umat,
    const ushortT* __restrict__ xgring, int xmask,
    ushortT* __restrict__ hring,
    unsigned* Fown,
    unsigned* Xown, int xph,
    unsigned* Xguard, int nGd,
    char* smem)
{
    constexpr int NGu   = 4 * U_;
    constexpr int WPG   = U_ / JCOLS;
    constexpr int JH    = JCOLS / 2;
    constexpr int TILES = JH / 16;
    constexpr int KT    = U_ / 32;
    constexpr int GR    = U_ / 8;
    constexpr int SG    = JCOLS / 32;    // xg mtiles (32-col) per gate slice
    constexpr int NX    = 4 * SG;

    ushortT* hstage = (ushortT*)smem;                    // [16][U]
    float*   ex     = (float*)(smem + 2 * 16 * U_);      // [3][2][JH][17]

    const int tid = threadIdx.x, w = tid >> 6, lane = tid & 63;
    const int lo = lane & 15, hi = lane >> 4;
    const int g4 = w & 3, chh = w >> 2;
    const int grp = rid & 7, wgj = rid >> 3;
    const int b0 = grp * 16, J = wgj * JCOLS;
    const size_t S = (size_t)128 * U_;

    int gc[TILES];
    #pragma unroll
    for (int tl = 0; tl < TILES; ++tl)
        gc[tl] = g4 * U_ + J + chh * JH + tl * 16 + lo;

    bf16x8 bfr[TILES][KT];
    #pragma unroll
    for (int tl = 0; tl < TILES; ++tl)
        #pragma unroll
        for (int kt = 0; kt < KT; ++kt) {
            const float* up = Umat + (size_t)(kt * 32 + hi * 8) * NGu + gc[tl];
            bf16x8 v;
            #pragma unroll
            for (int i = 0; i < 8; ++i) v[i] = (short)f2bf(up[(size_t)i * NGu]);
            bfr[tl][kt] = v;
        }

    float creg[TILES][4];
    #pragma unroll
    for (int tl = 0; tl < TILES; ++tl)
        #pragma unroll
        for (int r = 0; r < 4; ++r) creg[tl][r] = 0.f;

    for (int t = 0; t < SEQT; ++t) {
        if (w == 0) {
            int guard = 0; bool ok;
            do {
                bool pred = true;
                for (int i = lane; i < 2 * WPG; i += 64)
                    pred = pred && ((int)ald(&Fown[(grp * 2 * WPG + i) * 16]) >= t);
                if (Xown) {
                    for (int i = lane; i < NX; i += 64) {
                        const int gg = i / SG, ss = i - gg * SG;
                        const int mt = gg * (U_ / 32) + (J / 32) + ss;
                        const int fi = (xph == 2) ? (mt * 2 + (t & 1)) : mt;
                        pred = pred && ((int)ald(&Xown[fi * 16]) >= t + 1);
                    }
                }
                for (int i = lane; i < nGd; i += 64)
                    pred = pred && ((int)ald(&Xguard[i * 16]) >= t - (RING - 1));
                ok = __all(pred);
                if (!ok) __builtin_amdgcn_s_sleep(1);
            } while (!ok && ++guard < LIM);
            if (lane == 0)
                (void)__hip_atomic_load(&Fown[0], __ATOMIC_ACQUIRE, AGT);
        }
        __syncthreads();   // B1: deps satisfied

        // xg loads (bf16 slab t)
        u16x4 xr[TILES];
        const size_t xb = (size_t)((t & xmask) * 8 + grp) * NGu;
        #pragma unroll
        for (int tl = 0; tl < TILES; ++tl)
            xr[tl] = *(const u16x4*)(xgring + (xb + gc[tl]) * 16 + hi * 4);

        if (t > 0) {
            const ushortT* hsrc = hring + (size_t)((t - 1) & (RING - 1)) * S;
            for (int i = tid; i < 16 * GR; i += 512) {
                const int row = i / GR, gi = i - row * GR;
                const int gs = gi ^ (row & 7);
                *(u16x8*)&hstage[(row * GR + gs) * 8] =
                    *(const u16x8*)(hsrc + (size_t)(b0 + row) * U_ + gi * 8);
            }
        }
        __syncthreads();   // B2: h staged

        f32x4 acc[TILES];
        #pragma unroll
        for (int tl = 0; tl < TILES; ++tl) acc[tl] = f32x4{0.f, 0.f, 0.f, 0.f};
        if (t > 0) {
            #pragma unroll
            for (int kt = 0; kt < KT; ++kt) {
                const int gs = (kt * 4 + hi) ^ (lo & 7);
                const bf16x8 a = *(const bf16x8*)&hstage[(lo * GR + gs) * 8];
                #pragma unroll
                for (int tl = 0; tl < TILES; ++tl)
                    acc[tl] = __builtin_amdgcn_mfma_f32_16x16x32_bf16(a, bfr[tl][kt], acc[tl], 0, 0, 0);
            }
        }

        float p[TILES][4];
        #pragma unroll
        for (int tl = 0; tl < TILES; ++tl)
            #pragma unroll
            for (int r = 0; r < 4; ++r)
                p[tl][r] = acc[tl][r] + bf2f(xr[tl][r]);

        if (g4 != 2) {
            const int slot = (g4 == 3) ? 2 : g4;    // i->0, f->1, o->2
            #pragma unroll
            for (int tl = 0; tl < TILES; ++tl)
                #pragma unroll
                for (int r = 0; r < 4; ++r)
                    ex[((slot * 2 + chh) * JH + tl * 16 + lo) * 17 + hi * 4 + r] = sigmoidf_(p[tl][r]);
        }
        __syncthreads();   // B3: gates exchanged

        if (g4 == 2) {
            ushortT* hwr = hring + (size_t)(t & (RING - 1)) * S;
            #pragma unroll
            for (int tl = 0; tl < TILES; ++tl) {
                const int jh = tl * 16 + lo;
                const int j  = gc[tl] - 2 * U_;
                #pragma unroll
                for (int r = 0; r < 4; ++r) {
                    const int row = hi * 4 + r;
                    const float i_ = ex[((0 * 2 + chh) * JH + jh) * 17 + row];
                    const float f_ = ex[((1 * 2 + chh) * JH + jh) * 17 + row];
                    const float o_ = ex[((2 * 2 + chh) * JH + jh) * 17 + row];
                    creg[tl][r] = f_ * creg[tl][r] + i_ * fmaxf(p[tl][r], 0.f);
                    const float hn = o_ * fmaxf(creg[tl][r], 0.f);
                    hwr[(size_t)(b0 + row) * U_ + j] = f2bf(hn);
                }
            }
            asm volatile("s_waitcnt vmcnt(0)" ::: "memory");
            if (lane == 0)
                __hip_atomic_store(&Fown[((grp * WPG + wgj) * 2 + chh) * 16],
                                   (unsigned)(t + 1), __ATOMIC_RELEASE, AGT);
        }
        // next-iteration B1 syncthreads provides the intra-WG WAR fence
    }
}

// ---------------------------------------------------------------------------
// GEMM worker: 32 m-cols (W tile LDS-resident, staged ONCE), per step:
// poll upstream h flags >= t+1 & guard >= t-(RING-1); read h slab; MFMA;
// write xg slab tile bf16; release X flag.
// ---------------------------------------------------------------------------
template<int NGATES, int KP>
__device__ void worker_role(
    int mtile, int phase, int nph,
    const ushortT* __restrict__ WT,     // [NGATES][KP] bf16
    const float* __restrict__ bias,
    const ushortT* __restrict__ hring,  // [RING][128][KP]
    ushortT* __restrict__ xgring,       // [RING][8][NGATES][16]
    unsigned* Fup, int nUp,
    unsigned* Fguard, int nGd,
    unsigned* Xrel,
    char* smem)
{
    constexpr int GR2 = KP / 8;
    ushortT* Wl = (ushortT*)smem;                 // [32][KP] swizzled granules
    ushortT* Xl = (ushortT*)(smem + 32 * KP * 2); // [128][32]

    const int tid = threadIdx.x, w = tid >> 6, lane = tid & 63;
    const int lo = lane & 15, hi = lane >> 4;
    const int mt2 = w & 1, nh = w >> 1;
    const int m0 = mtile * 32;

    // stage W tile once
    for (int i = tid; i < 32 * GR2; i += 512) {
        const int row = i / GR2, gi = i - row * GR2;
        const int gs = gi ^ (row & 7);
        *(u16x8*)&Wl[(row * GR2 + gs) * 8] =
            *(const u16x8*)(WT + (size_t)(m0 + row) * KP + gi * 8);
    }
    __syncthreads();

    for (int t = phase; t < SEQT; t += nph) {
        if (w == 0) {
            int guard = 0; bool ok;
            do {
                bool pred = true;
                for (int i = lane; i < nUp; i += 64)
                    pred = pred && ((int)ald(&Fup[i * 16]) >= t + 1);
                for (int i = lane; i < nGd; i += 64)
                    pred = pred && ((int)ald(&Fguard[i * 16]) >= t - (RING - 1));
                ok = __all(pred);
                if (!ok) __builtin_amdgcn_s_sleep(1);
            } while (!ok && ++guard < LIM);
            if (lane == 0)
                (void)__hip_atomic_load(&Fup[0], __ATOMIC_ACQUIRE, AGT);
        }
        __syncthreads();

        const ushortT* hslab = hring + (size_t)(t & (RING - 1)) * 128 * KP;

        f32x4 acc[2];
        acc[0] = f32x4{0.f, 0.f, 0.f, 0.f};
        acc[1] = f32x4{0.f, 0.f, 0.f, 0.f};

        for (int k0 = 0; k0 < KP; k0 += 32) {
            {   // stage Xl: 128 rows x 4 granules (exactly 512 stores)
                const int row = tid >> 2, gq = tid & 3;
                const int gs = gq ^ ((row >> 1) & 3);
                *(u16x8*)&Xl[row * 32 + gs * 8] =
                    *(const u16x8*)(hslab + (size_t)row * KP + k0 + gq * 8);
            }
            __syncthreads();
            {
                const int arow = mt2 * 16 + lo;
                const int gsa = ((k0 >> 3) + hi) ^ (arow & 7);
                const bf16x8 a = *(const bf16x8*)&Wl[(arow * GR2 + gsa) * 8];
                #pragma unroll
                for (int nn = 0; nn < 2; ++nn) {
                    const int brow = nh * 32 + nn * 16 + lo;
                    const bf16x8 b = *(const bf16x8*)&Xl[brow * 32 + ((hi ^ ((brow >> 1) & 3))) * 8];
                    acc[nn] = __builtin_amdgcn_mfma_f32_16x16x32_bf16(a, b, acc[nn], 0, 0, 0);
                }
            }
            __syncthreads();
        }

        const size_t slab = (size_t)(t & (RING - 1)) * 8;
        #pragma unroll
        for (int nn = 0; nn < 2; ++nn) {
            const int bb = nh * 32 + nn * 16 + lo;
            #pragma unroll
            for (int j = 0; j < 4; ++j) {
                const int m = m0 + mt2 * 16 + hi * 4 + j;
                xgring[((slab + (bb >> 4)) * NGATES + m) * 16 + (bb & 15)] =
                    f2bf(acc[nn][j] + bias[m]);
            }
        }
        asm volatile("s_waitcnt vmcnt(0)" ::: "memory");
        __syncthreads();
        if (tid == 0)
            __hip_atomic_store(Xrel, (unsigned)(t + 1), __ATOMIC_RELEASE, AGT);
    }
}

// ---------------------------------------------------------------------------
// Megakernel args + role dispatch. Grid 224 x 512 thr, 1 WG/CU.
//  [0,16) L0  [16,80) L1  [80,96) L2  [96,160) G1 (64x1ph)  [160,224) G2 (32x2ph)
// ---------------------------------------------------------------------------
struct MegaArgs {
    const float *U0, *U1, *U2;
    const ushortT *W1T, *W2T;
    const float *b1, *b2;
    const ushortT* xg0;                 // [512][8][1024][16] precomputed
    ushortT *xg1, *xg2;                 // rings
    ushortT *h0r, *h1r, *h2r;           // rings
    unsigned *F0, *F1, *F2, *X1, *X2;
};

__global__ __launch_bounds__(512, 1) void mega(MegaArgs A)
{
    extern __shared__ char smem[];
    const int bid = blockIdx.x;
    if (bid < 16) {
        rec_role<NU0, 128>(bid, A.U0, A.xg0, 511, A.h0r, A.F0,
                           nullptr, 1, A.X1, 64, smem);
    } else if (bid < 80) {
        rec_role<NU1, 64>(bid - 16, A.U1, A.xg1, RING - 1, A.h1r, A.F1,
                          A.X1, 1, A.X2, 64, smem);
    } else if (bid < 96) {
        rec_role<NU2, 128>(bid - 80, A.U2, A.xg2, RING - 1, A.h2r, A.F2,
                           A.X2, 2, nullptr, 0, smem);
    } else if (bid < 160) {
        const int mt = bid - 96;
        worker_role<2048, 256>(mt, 0, 1, A.W1T, A.b1, A.h0r, A.xg1,
                               A.F0, 32, A.F1, 128, A.X1 + mt * 16, smem);
    } else {
        const int wid = bid - 160;
        const int mt = wid & 31, ph = wid >> 5;
        worker_role<1024, 512>(mt, ph, 2, A.W2T, A.b2, A.h1r, A.xg2,
                               A.F1, 128, A.F2, 32, A.X2 + (mt * 2 + ph) * 16, smem);
    }
}

// ---------------------------------------------------------------------------
// Head
// ---------------------------------------------------------------------------
__global__ __launch_bounds__(64) void head_kernel(
    const ushortT* __restrict__ h2,
    const float* __restrict__ Wd,
    const float* __restrict__ bd,
    const float* __restrict__ Wc,
    const float* __restrict__ bc,
    float* __restrict__ out)
{
    const int b = blockIdx.x;
    const int j = threadIdx.x;
    float a = bd[j];
    const ushortT* hrow = h2 + (size_t)b * NU2;
    #pragma unroll 4
    for (int k = 0; k < NU2; ++k)
        a += bf2f(hrow[k]) * Wd[(size_t)k * NDENSE + j];
    a = fmaxf(a, 0.f) * Wc[j];
    #pragma unroll
    for (int off = 32; off > 0; off >>= 1)
        a += __shfl_down(a, off);
    if (j == 0)
        out[b] = 1.f / (1.f + expf(-(a + bc[0])));
}

// ---------------------------------------------------------------------------
extern "C" void kernel_launch(void* const* d_in, const int* in_sizes, int n_in,
                              void* d_out, int out_size, void* d_ws, size_t ws_size,
                              hipStream_t stream)
{
    const int*   tokens = (const int*)  d_in[0];
    const float* emb    = (const float*)d_in[1];
    const float* W0     = (const float*)d_in[2];
    const float* Ur0    = (const float*)d_in[3];
    const float* b0v    = (const float*)d_in[4];
    const float* W1     = (const float*)d_in[5];
    const float* Ur1    = (const float*)d_in[6];
    const float* b1v    = (const float*)d_in[7];
    const float* W2     = (const float*)d_in[8];
    const float* Ur2    = (const float*)d_in[9];
    const float* b2v    = (const float*)d_in[10];
    const float* Wd     = (const float*)d_in[11];
    const float* bd     = (const float*)d_in[12];
    const float* Wc     = (const float*)d_in[13];
    const float* bc     = (const float*)d_in[14];
    float* out = (float*)d_out;

    char* p = (char*)d_ws;
    auto alloc = [&](size_t bytes) -> char* {
        char* q = p; p += (bytes + 255) & ~(size_t)255; return q;
    };
    ushortT* xg0   = (ushortT*)alloc((size_t)SEQT * 8 * 1024 * 16 * 2);  // 128 MB
    ushortT* xg1   = (ushortT*)alloc((size_t)RING * 8 * 2048 * 16 * 2);  // 8 MB
    ushortT* xg2   = (ushortT*)alloc((size_t)RING * 8 * 1024 * 16 * 2);  // 4 MB
    ushortT* h0r   = (ushortT*)alloc((size_t)RING * 128 * NU0 * 2);
    ushortT* h1r   = (ushortT*)alloc((size_t)RING * 128 * NU1 * 2);
    ushortT* h2r   = (ushortT*)alloc((size_t)RING * 128 * NU2 * 2);
    ushortT* W0T   = (ushortT*)alloc((size_t)1024 * KP0 * 2);
    ushortT* W1T   = (ushortT*)alloc((size_t)2048 * NU0 * 2);
    ushortT* W2T   = (ushortT*)alloc((size_t)1024 * NU1 * 2);
    ushortT* embbf = (ushortT*)alloc((size_t)VOCABN * KP0 * 2);
    unsigned* flg  = (unsigned*)alloc(32768);

    // flag partition (16-word stride per flag)
    unsigned* F0 = flg;             // 32  (16 L0 WGs x 2)
    unsigned* F1 = F0 + 32 * 16;    // 128 (64 L1 WGs x 2)
    unsigned* F2 = F1 + 128 * 16;   // 32  (16 L2 WGs x 2)
    unsigned* X1 = F2 + 32 * 16;    // 64  (G1 mtiles)
    unsigned* X2 = X1 + 64 * 16;    // 64  (32 G2 mtiles x 2 phases)

    hipMemsetAsync(flg, 0, 32768, stream);

    convert_WT<<<512, 256, 0, stream>>>(W0, W0T, EMB_D, 1024, KP0, 1024 * KP0);
    convert_WT<<<512, 256, 0, stream>>>(W1, W1T, NU0, 2048, NU0, 2048 * NU0);
    convert_WT<<<512, 256, 0, stream>>>(W2, W2T, NU1, 1024, NU1, 1024 * NU1);
    convert_emb<<<1024, 256, 0, stream>>>(emb, embbf);

    // precompute xg0 for all 512 steps (no recurrence dependency)
    gemm_xg0<<<dim3(SEQT, 8), 256, 0, stream>>>(embbf, tokens, W0T, b0v, xg0);

    MegaArgs A;
    A.U0 = Ur0; A.U1 = Ur1; A.U2 = Ur2;
    A.W1T = W1T; A.W2T = W2T;
    A.b1 = b1v; A.b2 = b2v;
    A.xg0 = xg0; A.xg1 = xg1; A.xg2 = xg2;
    A.h0r = h0r; A.h1r = h1r; A.h2r = h2r;
    A.F0 = F0; A.F1 = F1; A.F2 = F2; A.X1 = X1; A.X2 = X2;

    void* args[] = {&A};
    hipLaunchCooperativeKernel((void*)mega, dim3(224), dim3(512), args, 40960, stream);

    // final h of layer 2 = ring slab (511 & 15) = 15
    head_kernel<<<BATCH, 64, 0, stream>>>(h2r + (size_t)15 * 128 * NU2,
                                          Wd, bd, Wc, bc, out);
}

// Round 10
// 4640.104 us; speedup vs baseline: 1.1864x; 1.1864x over previous
//
#include <hip/hip_runtime.h>
#include <cstdint>
#include <cstddef>

#define BATCH  128
#define SEQT   512
#define EMB_D  300
#define VOCABN 5000
#define KP0    320
#define NU0    256
#define NU1    512
#define NU2    256
#define NDENSE 64
#define RING   16
#define LIM    (1 << 19)

typedef unsigned short ushortT;
typedef __attribute__((ext_vector_type(8))) short bf16x8;
typedef __attribute__((ext_vector_type(8))) unsigned short u16x8;
typedef __attribute__((ext_vector_type(4))) unsigned short u16x4;
typedef __attribute__((ext_vector_type(4))) float f32x4;

#define AGT __HIP_MEMORY_SCOPE_AGENT

static __device__ __forceinline__ unsigned short f2bf(float x) {
    union { float f; unsigned u; } v; v.f = x;
    const unsigned r = v.u + 0x7FFFu + ((v.u >> 16) & 1u);
    return (unsigned short)(r >> 16);
}
static __device__ __forceinline__ float bf2f(unsigned short b) {
    union { unsigned u; float f; } v; v.u = ((unsigned)b) << 16;
    return v.f;
}
static __device__ __forceinline__ float sigmoidf_(float x) {
    return 1.f / (1.f + __expf(-x));
}
static __device__ __forceinline__ unsigned ald(const unsigned* p) {
    return __hip_atomic_load((unsigned*)p, __ATOMIC_RELAXED, AGT);
}
static __device__ __forceinline__ void ast(unsigned* p, unsigned v) {
    __hip_atomic_store(p, v, __ATOMIC_RELAXED, AGT);
}
// device-coherent 16B load (4 independent LLC-direct dword loads)
static __device__ __forceinline__ u16x8 ldA8(const ushortT* p) {
    const unsigned* q = (const unsigned*)p;
    union { unsigned u[4]; u16x8 v; } r;
    r.u[0] = ald(q + 0); r.u[1] = ald(q + 1);
    r.u[2] = ald(q + 2); r.u[3] = ald(q + 3);
    return r.v;
}

// ---------------------------------------------------------------------------
// One-time converts
// ---------------------------------------------------------------------------
__global__ __launch_bounds__(256) void convert_WT(
    const float* __restrict__ W, ushortT* __restrict__ WbfT,
    int K, int NG, int KP, int total)
{
    for (int idx = blockIdx.x * 256 + threadIdx.x; idx < total; idx += gridDim.x * 256) {
        const int m = idx / KP, k = idx - m * KP;
        WbfT[idx] = (k < K) ? f2bf(W[(size_t)k * NG + m]) : (ushortT)0;
    }
}
__global__ __launch_bounds__(256) void convert_emb(
    const float* __restrict__ emb, ushortT* __restrict__ embbf)
{
    const int total = VOCABN * KP0;
    for (int idx = blockIdx.x * 256 + threadIdx.x; idx < total; idx += gridDim.x * 256) {
        const int v = idx / KP0, k = idx - v * KP0;
        embbf[idx] = (k < EMB_D) ? f2bf(emb[(size_t)v * EMB_D + k]) : (ushortT)0;
    }
}

// ---------------------------------------------------------------------------
// Precompute ALL of xg0: xg0[t][g][m][b16] bf16 (no recurrence dependency).
// ---------------------------------------------------------------------------
__global__ __launch_bounds__(256) void gemm_xg0(
    const ushortT* __restrict__ embbf,
    const int*   __restrict__ tokens,
    const ushortT* __restrict__ W0T,     // [1024][KP0]
    const float* __restrict__ bias,
    ushortT* __restrict__ xg0)           // [512][8][1024][16]
{
    __shared__ ushortT Wl[128][32];
    __shared__ ushortT Xl[128][32];
    __shared__ int tokL[128];

    const int tid = threadIdx.x;
    const int t   = blockIdx.x;
    const int m0  = blockIdx.y * 128;
    const int wv  = tid >> 6;
    const int lane = tid & 63;
    const int lo  = lane & 15;
    const int hi  = lane >> 4;

    if (tid < 128) tokL[tid] = tokens[tid * SEQT + t];
    __syncthreads();

    f32x4 acc[2][8];
    #pragma unroll
    for (int s = 0; s < 2; ++s)
        #pragma unroll
        for (int n = 0; n < 8; ++n)
            acc[s][n] = f32x4{0.f, 0.f, 0.f, 0.f};

    for (int k0 = 0; k0 < KP0; k0 += 32) {
        #pragma unroll
        for (int it = 0; it < 2; ++it) {
            const int idx = tid + it * 256;
            const int row = idx >> 2, gq = idx & 3;
            const int gs  = gq ^ ((row >> 1) & 3);
            *(u16x8*)&Wl[row][gs * 8] =
                *(const u16x8*)(W0T + (size_t)(m0 + row) * KP0 + k0 + gq * 8);
            *(u16x8*)&Xl[row][gs * 8] =
                *(const u16x8*)(embbf + (size_t)tokL[row] * KP0 + k0 + gq * 8);
        }
        __syncthreads();

        bf16x8 bfr[8];
        #pragma unroll
        for (int n = 0; n < 8; ++n) {
            const int row = n * 16 + lo;
            bfr[n] = *(const bf16x8*)&Xl[row][(hi ^ ((row >> 1) & 3)) * 8];
        }
        #pragma unroll
        for (int s = 0; s < 2; ++s) {
            const int row = wv * 32 + s * 16 + lo;
            const bf16x8 a = *(const bf16x8*)&Wl[row][(hi ^ ((row >> 1) & 3)) * 8];
            #pragma unroll
            for (int n = 0; n < 8; ++n)
                acc[s][n] = __builtin_amdgcn_mfma_f32_16x16x32_bf16(a, bfr[n], acc[s][n], 0, 0, 0);
        }
        __syncthreads();
    }

    #pragma unroll
    for (int s = 0; s < 2; ++s)
        #pragma unroll
        for (int j = 0; j < 4; ++j) {
            const int m = m0 + wv * 32 + s * 16 + hi * 4 + j;
            const float bi = bias[m];
            #pragma unroll
            for (int n = 0; n < 8; ++n)
                xg0[(((size_t)t * 8 + n) * 1024 + m) * 16 + lo] = f2bf(acc[s][n][j] + bi);
        }
}

// ---------------------------------------------------------------------------
// Recurrence role (flushless). Group grp = rid&7 owns 16 b rows; WG owns
// JCOLS h-cols x 4 gates (wave w: gate w&3, col-half w>>2). U cols persistent
// bf16 B-frags. All cross-WG payloads via relaxed LLC-direct atomics; h writes
// pair-packed u32; flag stored after per-wave vmcnt(0) drain.
// ---------------------------------------------------------------------------
template<int U_, int JCOLS, bool XATOMIC>
__device__ void rec_role(
    int rid,
    const float* __restrict__ Umat,
    const ushortT* __restrict__ xgring, int xmask,
    ushortT* __restrict__ hring,
    unsigned* Fown,
    unsigned* Xown,            // 2-phase worker flags or nullptr
    unsigned* Xguard, int nGd,
    char* smem)
{
    constexpr int NGu   = 4 * U_;
    constexpr int WPG   = U_ / JCOLS;
    constexpr int JH    = JCOLS / 2;
    constexpr int TILES = JH / 16;
    constexpr int KT    = U_ / 32;
    constexpr int GR    = U_ / 8;
    constexpr int MPG   = JCOLS / 64;   // 64-col xg m-tiles per gate slice
    constexpr int NX    = 4 * MPG;

    ushortT* hstage = (ushortT*)smem;                    // [16][U]
    float*   ex     = (float*)(smem + 2 * 16 * U_);      // [3][2][JH][17]

    const int tid = threadIdx.x, w = tid >> 6, lane = tid & 63;
    const int lo = lane & 15, hi = lane >> 4;
    const int g4 = w & 3, chh = w >> 2;
    const int grp = rid & 7, wgj = rid >> 3;
    const int b0 = grp * 16, J = wgj * JCOLS;
    const size_t S = (size_t)128 * U_;

    int gc[TILES];
    #pragma unroll
    for (int tl = 0; tl < TILES; ++tl)
        gc[tl] = g4 * U_ + J + chh * JH + tl * 16 + lo;

    bf16x8 bfr[TILES][KT];
    #pragma unroll
    for (int tl = 0; tl < TILES; ++tl)
        #pragma unroll
        for (int kt = 0; kt < KT; ++kt) {
            const float* up = Umat + (size_t)(kt * 32 + hi * 8) * NGu + gc[tl];
            bf16x8 v;
            #pragma unroll
            for (int i = 0; i < 8; ++i) v[i] = (short)f2bf(up[(size_t)i * NGu]);
            bfr[tl][kt] = v;
        }

    float creg[TILES][4];
    #pragma unroll
    for (int tl = 0; tl < TILES; ++tl)
        #pragma unroll
        for (int r = 0; r < 4; ++r) creg[tl][r] = 0.f;

    for (int t = 0; t < SEQT; ++t) {
        if (w == 0) {
            if (t > 0) {   // critical: own-group h flags
                int guard = 0; bool ok;
                do {
                    bool pred = true;
                    for (int i = lane; i < 2 * WPG; i += 64)
                        pred = pred && ((int)ald(&Fown[(grp * 2 * WPG + i) * 16]) >= t);
                    ok = __all(pred);
                    if (!ok) __builtin_amdgcn_s_sleep(1);
                } while (!ok && ++guard < LIM);
            }
            {   // non-critical: xg ready + ring guard
                int guard = 0; bool ok;
                do {
                    bool pred = true;
                    if (XATOMIC && Xown) {
                        for (int i = lane; i < NX; i += 64) {
                            const int gg = i / MPG, ss = i - gg * MPG;
                            const int mt = (gg * U_ + J) / 64 + ss;
                            pred = pred && ((int)ald(&Xown[(mt * 2 + (t & 1)) * 16]) >= t + 1);
                        }
                    }
                    for (int i = lane; i < nGd; i += 64)
                        pred = pred && ((int)ald(&Xguard[i * 16]) >= t - (RING - 1));
                    ok = __all(pred);
                    if (!ok) __builtin_amdgcn_s_sleep(1);
                } while (!ok && ++guard < LIM);
            }
        }
        __syncthreads();   // B1: deps satisfied

        // xg load (bf16 slab t)
        u16x4 xr[TILES];
        const size_t xb = (size_t)((t & xmask) * 8 + grp) * NGu;
        #pragma unroll
        for (int tl = 0; tl < TILES; ++tl) {
            if (XATOMIC) {
                const unsigned* q = (const unsigned*)(xgring + (xb + gc[tl]) * 16 + hi * 4);
                union { unsigned u[2]; u16x4 v; } r;
                r.u[0] = ald(q); r.u[1] = ald(q + 1);
                xr[tl] = r.v;
            } else {
                xr[tl] = *(const u16x4*)(xgring + (xb + gc[tl]) * 16 + hi * 4);
            }
        }

        if (t > 0) {
            const ushortT* hsrc = hring + (size_t)((t - 1) & (RING - 1)) * S;
            for (int i = tid; i < 16 * GR; i += 512) {
                const int row = i / GR, gi = i - row * GR;
                const int gs = gi ^ (row & 7);
                *(u16x8*)&hstage[(row * GR + gs) * 8] =
                    ldA8(hsrc + (size_t)(b0 + row) * U_ + gi * 8);
            }
        }
        __syncthreads();   // B2: h staged

        f32x4 acc[TILES];
        #pragma unroll
        for (int tl = 0; tl < TILES; ++tl) acc[tl] = f32x4{0.f, 0.f, 0.f, 0.f};
        if (t > 0) {
            #pragma unroll
            for (int kt = 0; kt < KT; ++kt) {
                const int gs = (kt * 4 + hi) ^ (lo & 7);
                const bf16x8 a = *(const bf16x8*)&hstage[(lo * GR + gs) * 8];
                #pragma unroll
                for (int tl = 0; tl < TILES; ++tl)
                    acc[tl] = __builtin_amdgcn_mfma_f32_16x16x32_bf16(a, bfr[tl][kt], acc[tl], 0, 0, 0);
            }
        }

        float p[TILES][4];
        #pragma unroll
        for (int tl = 0; tl < TILES; ++tl)
            #pragma unroll
            for (int r = 0; r < 4; ++r)
                p[tl][r] = acc[tl][r] + bf2f(xr[tl][r]);

        if (g4 != 2) {
            const int slot = (g4 == 3) ? 2 : g4;    // i->0, f->1, o->2
            #pragma unroll
            for (int tl = 0; tl < TILES; ++tl)
                #pragma unroll
                for (int r = 0; r < 4; ++r)
                    ex[((slot * 2 + chh) * JH + tl * 16 + lo) * 17 + hi * 4 + r] = sigmoidf_(p[tl][r]);
        }
        __syncthreads();   // B3: gates exchanged

        if (g4 == 2) {
            ushortT* hwr = hring + (size_t)(t & (RING - 1)) * S;
            #pragma unroll
            for (int tl = 0; tl < TILES; ++tl) {
                const int j = gc[tl] - 2 * U_;
                unsigned own[4], oth[4];
                #pragma unroll
                for (int r = 0; r < 4; ++r) {
                    const int row = hi * 4 + r;
                    const float i_ = ex[((0 * 2 + chh) * JH + (j - J - chh * JH)) * 17 + row];
                    const float f_ = ex[((1 * 2 + chh) * JH + (j - J - chh * JH)) * 17 + row];
                    const float o_ = ex[((2 * 2 + chh) * JH + (j - J - chh * JH)) * 17 + row];
                    creg[tl][r] = f_ * creg[tl][r] + i_ * fmaxf(p[tl][r], 0.f);
                    const float hn = o_ * fmaxf(creg[tl][r], 0.f);
                    own[r] = (unsigned)f2bf(hn);
                }
                #pragma unroll
                for (int r = 0; r < 4; ++r)
                    oth[r] = (unsigned)__shfl_xor((int)own[r], 1);
                const int odd = lo & 1;
                const int rb = odd ? 2 : 0;
                const int je = j - odd;
                #pragma unroll
                for (int q = 0; q < 2; ++q) {
                    const int r = rb + q;
                    const unsigned pk = odd ? (oth[r] | (own[r] << 16))
                                            : (own[r] | (oth[r] << 16));
                    ast((unsigned*)&hwr[(size_t)(b0 + hi * 4 + r) * U_ + je], pk);
                }
            }
            asm volatile("s_waitcnt vmcnt(0)" ::: "memory");
            if (lane == 0)
                ast(&Fown[((grp * WPG + wgj) * 2 + chh) * 16], (unsigned)(t + 1));
        }
    }
}

// ---------------------------------------------------------------------------
// GEMM worker (flushless, double-buffered): 64 m-cols, W in LDS once, h slab
// read via LLC-direct atomics with reg-staged k-pipeline, packed xg stores.
// ---------------------------------------------------------------------------
template<int NGATES, int KP>
__device__ void worker_role(
    int mtile, int phase, int nph,
    const ushortT* __restrict__ WT,     // [NGATES][KP] bf16
    const float* __restrict__ bias,
    const ushortT* __restrict__ hring,  // [RING][128][KP]
    ushortT* __restrict__ xgring,       // [RING][8][NGATES][16]
    unsigned* Fup, int nUp,
    unsigned* Fguard, int nGd,
    unsigned* Xrel,
    char* smem)
{
    constexpr int GR2 = KP / 8;
    constexpr int NIT = KP / 32;
    ushortT* Wl = (ushortT*)smem;                   // [64][KP] swizzled granules
    ushortT* Xl = (ushortT*)(smem + 64 * KP * 2);   // 2 x [128][32]

    const int tid = threadIdx.x, w = tid >> 6, lane = tid & 63;
    const int lo = lane & 15, hi = lane >> 4;
    const int mq = w & 3, bh = w >> 2;
    const int m0 = mtile * 64;
    const int row = tid >> 2, gq = tid & 3;
    const int gsx = gq ^ ((row >> 1) & 3);

    // stage W tile once
    for (int i = tid; i < 64 * GR2; i += 512) {
        const int r_ = i / GR2, gi = i - r_ * GR2;
        const int gs = gi ^ (r_ & 7);
        *(u16x8*)&Wl[(r_ * GR2 + gs) * 8] =
            *(const u16x8*)(WT + (size_t)(m0 + r_) * KP + gi * 8);
    }
    // hoist bias
    float bv[4];
    #pragma unroll
    for (int j = 0; j < 4; ++j) bv[j] = bias[m0 + mq * 16 + hi * 4 + j];
    __syncthreads();

    for (int t = phase; t < SEQT; t += nph) {
        if (w == 0) {
            int guard = 0; bool ok;
            do {
                bool pred = true;
                for (int i = lane; i < nUp; i += 64)
                    pred = pred && ((int)ald(&Fup[i * 16]) >= t + 1);
                ok = __all(pred);
                if (!ok) __builtin_amdgcn_s_sleep(1);
            } while (!ok && ++guard < LIM);
            guard = 0;
            do {
                bool pred = true;
                for (int i = lane; i < nGd; i += 64)
                    pred = pred && ((int)ald(&Fguard[i * 16]) >= t - (RING - 1));
                ok = __all(pred);
                if (!ok) __builtin_amdgcn_s_sleep(1);
            } while (!ok && ++guard < LIM);
        }
        __syncthreads();

        const ushortT* hslab = hring + (size_t)(t & (RING - 1)) * 128 * KP;

        f32x4 acc[4];
        #pragma unroll
        for (int nn = 0; nn < 4; ++nn) acc[nn] = f32x4{0.f, 0.f, 0.f, 0.f};

        u16x8 R = ldA8(hslab + (size_t)row * KP + gq * 8);
        for (int it = 0; it < NIT; ++it) {
            ushortT* Xc = Xl + (it & 1) * (128 * 32);
            *(u16x8*)&Xc[row * 32 + gsx * 8] = R;
            if (it + 1 < NIT)
                R = ldA8(hslab + (size_t)row * KP + (it + 1) * 32 + gq * 8);
            __syncthreads();
            const int k0 = it * 32;
            const int arow = mq * 16 + lo;
            const int gsa = ((k0 >> 3) + hi) ^ (arow & 7);
            const bf16x8 a = *(const bf16x8*)&Wl[(arow * GR2 + gsa) * 8];
            #pragma unroll
            for (int nn = 0; nn < 4; ++nn) {
                const int brow = bh * 64 + nn * 16 + lo;
                const bf16x8 b = *(const bf16x8*)&Xc[brow * 32 + (hi ^ ((brow >> 1) & 3)) * 8];
                acc[nn] = __builtin_amdgcn_mfma_f32_16x16x32_bf16(a, b, acc[nn], 0, 0, 0);
            }
        }

        // packed epilogue: adjacent-b pairs -> u32 atomic stores
        const size_t slab = (size_t)(t & (RING - 1)) * 8;
        #pragma unroll
        for (int nn = 0; nn < 4; ++nn) {
            const int b = bh * 64 + nn * 16 + lo;
            unsigned own[4], oth[4];
            #pragma unroll
            for (int j = 0; j < 4; ++j)
                own[j] = (unsigned)f2bf(acc[nn][j] + bv[j]);
            #pragma unroll
            for (int j = 0; j < 4; ++j)
                oth[j] = (unsigned)__shfl_xor((int)own[j], 1);
            const int odd = lo & 1;
            const int jb = odd ? 2 : 0;
            const int be = (b & 15) - odd;
            #pragma unroll
            for (int q = 0; q < 2; ++q) {
                const int j = jb + q;
                const int m = m0 + mq * 16 + hi * 4 + j;
                const unsigned pk = odd ? (oth[j] | (own[j] << 16))
                                        : (own[j] | (oth[j] << 16));
                ast((unsigned*)&xgring[((slab + (b >> 4)) * NGATES + m) * 16 + be], pk);
            }
        }
        asm volatile("s_waitcnt vmcnt(0)" ::: "memory");
        __syncthreads();
        if (tid == 0)
            ast(Xrel, (unsigned)(t + 1));
    }
}

// ---------------------------------------------------------------------------
// Megakernel. Grid 192 x 512 thr, 1 WG/CU.
//  [0,16) L0  [16,80) L1  [80,96) L2  [96,160) G1 (32mt x 2ph)  [160,192) G2 (16mt x 2ph)
// ---------------------------------------------------------------------------
struct MegaArgs {
    const float *U0, *U1, *U2;
    const ushortT *W1T, *W2T;
    const float *b1, *b2;
    const ushortT* xg0;
    ushortT *xg1, *xg2;
    ushortT *h0r, *h1r, *h2r;
    unsigned *F0, *F1, *F2, *X1, *X2;
};

__global__ __launch_bounds__(512, 1) void mega(MegaArgs A)
{
    extern __shared__ char smem[];
    const int bid = blockIdx.x;
    if (bid < 16) {
        rec_role<NU0, 128, false>(bid, A.U0, A.xg0, 511, A.h0r, A.F0,
                                  nullptr, A.X1, 64, smem);
    } else if (bid < 80) {
        rec_role<NU1, 64, true>(bid - 16, A.U1, A.xg1, RING - 1, A.h1r, A.F1,
                                A.X1, A.X2, 32, smem);
    } else if (bid < 96) {
        rec_role<NU2, 128, true>(bid - 80, A.U2, A.xg2, RING - 1, A.h2r, A.F2,
                                 A.X2, nullptr, 0, smem);
    } else if (bid < 160) {
        const int wid = bid - 96;
        const int mt = wid & 31, ph = wid >> 5;
        worker_role<2048, 256>(mt, ph, 2, A.W1T, A.b1, A.h0r, A.xg1,
                               A.F0, 32, A.F1, 128, A.X1 + (mt * 2 + ph) * 16, smem);
    } else {
        const int wid = bid - 160;
        const int mt = wid & 15, ph = wid >> 4;
        worker_role<1024, 512>(mt, ph, 2, A.W2T, A.b2, A.h1r, A.xg2,
                               A.F1, 128, A.F2, 32, A.X2 + (mt * 2 + ph) * 16, smem);
    }
}

// ---------------------------------------------------------------------------
// Head
// ---------------------------------------------------------------------------
__global__ __launch_bounds__(64) void head_kernel(
    const ushortT* __restrict__ h2,
    const float* __restrict__ Wd,
    const float* __restrict__ bd,
    const float* __restrict__ Wc,
    const float* __restrict__ bc,
    float* __restrict__ out)
{
    const int b = blockIdx.x;
    const int j = threadIdx.x;
    float a = bd[j];
    const ushortT* hrow = h2 + (size_t)b * NU2;
    #pragma unroll 4
    for (int k = 0; k < NU2; ++k)
        a += bf2f(hrow[k]) * Wd[(size_t)k * NDENSE + j];
    a = fmaxf(a, 0.f) * Wc[j];
    #pragma unroll
    for (int off = 32; off > 0; off >>= 1)
        a += __shfl_down(a, off);
    if (j == 0)
        out[b] = 1.f / (1.f + expf(-(a + bc[0])));
}

// ---------------------------------------------------------------------------
extern "C" void kernel_launch(void* const* d_in, const int* in_sizes, int n_in,
                              void* d_out, int out_size, void* d_ws, size_t ws_size,
                              hipStream_t stream)
{
    const int*   tokens = (const int*)  d_in[0];
    const float* emb    = (const float*)d_in[1];
    const float* W0     = (const float*)d_in[2];
    const float* Ur0    = (const float*)d_in[3];
    const float* b0v    = (const float*)d_in[4];
    const float* W1     = (const float*)d_in[5];
    const float* Ur1    = (const float*)d_in[6];
    const float* b1v    = (const float*)d_in[7];
    const float* W2     = (const float*)d_in[8];
    const float* Ur2    = (const float*)d_in[9];
    const float* b2v    = (const float*)d_in[10];
    const float* Wd     = (const float*)d_in[11];
    const float* bd     = (const float*)d_in[12];
    const float* Wc     = (const float*)d_in[13];
    const float* bc     = (const float*)d_in[14];
    float* out = (float*)d_out;

    char* p = (char*)d_ws;
    auto alloc = [&](size_t bytes) -> char* {
        char* q = p; p += (bytes + 255) & ~(size_t)255; return q;
    };
    ushortT* xg0   = (ushortT*)alloc((size_t)SEQT * 8 * 1024 * 16 * 2);  // 128 MB
    ushortT* xg1   = (ushortT*)alloc((size_t)RING * 8 * 2048 * 16 * 2);  // 8 MB
    ushortT* xg2   = (ushortT*)alloc((size_t)RING * 8 * 1024 * 16 * 2);  // 4 MB
    ushortT* h0r   = (ushortT*)alloc((size_t)RING * 128 * NU0 * 2);
    ushortT* h1r   = (ushortT*)alloc((size_t)RING * 128 * NU1 * 2);
    ushortT* h2r   = (ushortT*)alloc((size_t)RING * 128 * NU2 * 2);
    ushortT* W0T   = (ushortT*)alloc((size_t)1024 * KP0 * 2);
    ushortT* W1T   = (ushortT*)alloc((size_t)2048 * NU0 * 2);
    ushortT* W2T   = (ushortT*)alloc((size_t)1024 * NU1 * 2);
    ushortT* embbf = (ushortT*)alloc((size_t)VOCABN * KP0 * 2);
    unsigned* flg  = (unsigned*)alloc(32768);

    // flag partition (16-word stride)
    unsigned* F0 = flg;             // 32  (16 L0 WGs x 2 c-waves)
    unsigned* F1 = F0 + 32 * 16;    // 128 (64 L1 WGs x 2)
    unsigned* F2 = F1 + 128 * 16;   // 32  (16 L2 WGs x 2)
    unsigned* X1 = F2 + 32 * 16;    // 64  (32 G1 mtiles x 2 phases)
    unsigned* X2 = X1 + 64 * 16;    // 32  (16 G2 mtiles x 2 phases)

    hipMemsetAsync(flg, 0, 32768, stream);

    convert_WT<<<512, 256, 0, stream>>>(W0, W0T, EMB_D, 1024, KP0, 1024 * KP0);
    convert_WT<<<512, 256, 0, stream>>>(W1, W1T, NU0, 2048, NU0, 2048 * NU0);
    convert_WT<<<512, 256, 0, stream>>>(W2, W2T, NU1, 1024, NU1, 1024 * NU1);
    convert_emb<<<1024, 256, 0, stream>>>(emb, embbf);

    gemm_xg0<<<dim3(SEQT, 8), 256, 0, stream>>>(embbf, tokens, W0T, b0v, xg0);

    MegaArgs A;
    A.U0 = Ur0; A.U1 = Ur1; A.U2 = Ur2;
    A.W1T = W1T; A.W2T = W2T;
    A.b1 = b1v; A.b2 = b2v;
    A.xg0 = xg0; A.xg1 = xg1; A.xg2 = xg2;
    A.h0r = h0r; A.h1r = h1r; A.h2r = h2r;
    A.F0 = F0; A.F1 = F1; A.F2 = F2; A.X1 = X1; A.X2 = X2;

    void* args[] = {&A};
    // smem: max(rec NU0 34304, G2 worker 64*512*2 + 2*128*32*2 = 81920)
    hipLaunchCooperativeKernel((void*)mega, dim3(192), dim3(512), args, 81920, stream);

    // final h of layer 2 = ring slab (511 & 15) = 15
    head_kernel<<<BATCH, 64, 0, stream>>>(h2r + (size_t)15 * 128 * NU2,
                                          Wd, bd, Wc, bc, out);
}

// Round 11
// 2757.706 us; speedup vs baseline: 1.9962x; 1.6826x over previous
//
#include <hip/hip_runtime.h>
#include <cstdint>
#include <cstddef>

#define BATCH  128
#define SEQT   512
#define EMB_D  300
#define VOCABN 5000
#define KP0    320
#define NU0    256
#define NU1    512
#define NU2    256
#define NDENSE 64
#define RING   32
#define LIM    (1 << 19)

typedef unsigned short ushortT;
typedef unsigned long long ull;
typedef __attribute__((ext_vector_type(8))) short bf16x8;
typedef __attribute__((ext_vector_type(8))) unsigned short u16x8;
typedef __attribute__((ext_vector_type(4))) unsigned short u16x4;
typedef __attribute__((ext_vector_type(4))) float f32x4;

#define AGT __HIP_MEMORY_SCOPE_AGENT

static __device__ __forceinline__ unsigned short f2bf(float x) {
    union { float f; unsigned u; } v; v.f = x;
    const unsigned r = v.u + 0x7FFFu + ((v.u >> 16) & 1u);
    return (unsigned short)(r >> 16);
}
static __device__ __forceinline__ float bf2f(unsigned short b) {
    union { unsigned u; float f; } v; v.u = ((unsigned)b) << 16;
    return v.f;
}
static __device__ __forceinline__ float sigmoidf_(float x) {
    return 1.f / (1.f + __expf(-x));
}
static __device__ __forceinline__ unsigned ald(const unsigned* p) {
    return __hip_atomic_load((unsigned*)p, __ATOMIC_RELAXED, AGT);
}
static __device__ __forceinline__ void ast(unsigned* p, unsigned v) {
    __hip_atomic_store(p, v, __ATOMIC_RELAXED, AGT);
}
// device-coherent 16B load as 2 x dwordx2 atomics
static __device__ __forceinline__ u16x8 ldG16(const ushortT* p) {
    const ull* q = (const ull*)p;
    union { ull u[2]; u16x8 v; } r;
    r.u[0] = __hip_atomic_load((ull*)q,     __ATOMIC_RELAXED, AGT);
    r.u[1] = __hip_atomic_load((ull*)q + 1, __ATOMIC_RELAXED, AGT);
    return r.v;
}
static __device__ __forceinline__ u16x4 ldG8(const ushortT* p) {
    union { ull u; u16x4 v; } r;
    r.u = __hip_atomic_load((const ull*)p, __ATOMIC_RELAXED, AGT);
    return r.v;
}

// ---------------------------------------------------------------------------
// One-time converts
// ---------------------------------------------------------------------------
__global__ __launch_bounds__(256) void convert_WT(
    const float* __restrict__ W, ushortT* __restrict__ WbfT,
    int K, int NG, int KP, int total)
{
    for (int idx = blockIdx.x * 256 + threadIdx.x; idx < total; idx += gridDim.x * 256) {
        const int m = idx / KP, k = idx - m * KP;
        WbfT[idx] = (k < K) ? f2bf(W[(size_t)k * NG + m]) : (ushortT)0;
    }
}
__global__ __launch_bounds__(256) void convert_emb(
    const float* __restrict__ emb, ushortT* __restrict__ embbf)
{
    const int total = VOCABN * KP0;
    for (int idx = blockIdx.x * 256 + threadIdx.x; idx < total; idx += gridDim.x * 256) {
        const int v = idx / KP0, k = idx - v * KP0;
        embbf[idx] = (k < EMB_D) ? f2bf(emb[(size_t)v * EMB_D + k]) : (ushortT)0;
    }
}

// ---------------------------------------------------------------------------
// Precompute ALL of xg0: xg0[t][g][m][b16] bf16 (no recurrence dependency).
// ---------------------------------------------------------------------------
__global__ __launch_bounds__(256) void gemm_xg0(
    const ushortT* __restrict__ embbf,
    const int*   __restrict__ tokens,
    const ushortT* __restrict__ W0T,     // [1024][KP0]
    const float* __restrict__ bias,
    ushortT* __restrict__ xg0)           // [512][8][1024][16]
{
    __shared__ ushortT Wl[128][32];
    __shared__ ushortT Xl[128][32];
    __shared__ int tokL[128];

    const int tid = threadIdx.x;
    const int t   = blockIdx.x;
    const int m0  = blockIdx.y * 128;
    const int wv  = tid >> 6;
    const int lane = tid & 63;
    const int lo  = lane & 15;
    const int hi  = lane >> 4;

    if (tid < 128) tokL[tid] = tokens[tid * SEQT + t];
    __syncthreads();

    f32x4 acc[2][8];
    #pragma unroll
    for (int s = 0; s < 2; ++s)
        #pragma unroll
        for (int n = 0; n < 8; ++n)
            acc[s][n] = f32x4{0.f, 0.f, 0.f, 0.f};

    for (int k0 = 0; k0 < KP0; k0 += 32) {
        #pragma unroll
        for (int it = 0; it < 2; ++it) {
            const int idx = tid + it * 256;
            const int row = idx >> 2, gq = idx & 3;
            const int gs  = gq ^ ((row >> 1) & 3);
            *(u16x8*)&Wl[row][gs * 8] =
                *(const u16x8*)(W0T + (size_t)(m0 + row) * KP0 + k0 + gq * 8);
            *(u16x8*)&Xl[row][gs * 8] =
                *(const u16x8*)(embbf + (size_t)tokL[row] * KP0 + k0 + gq * 8);
        }
        __syncthreads();

        bf16x8 bfr[8];
        #pragma unroll
        for (int n = 0; n < 8; ++n) {
            const int row = n * 16 + lo;
            bfr[n] = *(const bf16x8*)&Xl[row][(hi ^ ((row >> 1) & 3)) * 8];
        }
        #pragma unroll
        for (int s = 0; s < 2; ++s) {
            const int row = wv * 32 + s * 16 + lo;
            const bf16x8 a = *(const bf16x8*)&Wl[row][(hi ^ ((row >> 1) & 3)) * 8];
            #pragma unroll
            for (int n = 0; n < 8; ++n)
                acc[s][n] = __builtin_amdgcn_mfma_f32_16x16x32_bf16(a, bfr[n], acc[s][n], 0, 0, 0);
        }
        __syncthreads();
    }

    #pragma unroll
    for (int s = 0; s < 2; ++s)
        #pragma unroll
        for (int j = 0; j < 4; ++j) {
            const int m = m0 + wv * 32 + s * 16 + hi * 4 + j;
            const float bi = bias[m];
            #pragma unroll
            for (int n = 0; n < 8; ++n)
                xg0[(((size_t)t * 8 + n) * 1024 + m) * 16 + lo] = f2bf(acc[s][n][j] + bi);
        }
}

// ---------------------------------------------------------------------------
// Recurrence role (flushless). Group grp = rid&7 owns 16 b rows; WG owns
// JCOLS h-cols x 4 gates. Critical poll (own-group h flags) tight; xg-ready
// and ring-guard polls throttled (s_sleep 8). u64 atomic payload transfers.
// ---------------------------------------------------------------------------
template<int U_, int JCOLS, bool XATOMIC>
__device__ void rec_role(
    int rid,
    const float* __restrict__ Umat,
    const ushortT* __restrict__ xgring, int xmask,
    ushortT* __restrict__ hring,
    unsigned* Fown,
    unsigned* Xown, int xph, int xmsh,
    unsigned* Xguard, int nGd,
    char* smem)
{
    constexpr int NGu   = 4 * U_;
    constexpr int WPG   = U_ / JCOLS;
    constexpr int JH    = JCOLS / 2;
    constexpr int TILES = JH / 16;
    constexpr int KT    = U_ / 32;
    constexpr int GR    = U_ / 8;

    ushortT* hstage = (ushortT*)smem;                    // [16][U]
    float*   ex     = (float*)(smem + 2 * 16 * U_);      // [3][2][JH][17]

    const int tid = threadIdx.x, w = tid >> 6, lane = tid & 63;
    const int lo = lane & 15, hi = lane >> 4;
    const int g4 = w & 3, chh = w >> 2;
    const int grp = rid & 7, wgj = rid >> 3;
    const int b0 = grp * 16, J = wgj * JCOLS;
    const size_t S = (size_t)128 * U_;

    int gc[TILES];
    #pragma unroll
    for (int tl = 0; tl < TILES; ++tl)
        gc[tl] = g4 * U_ + J + chh * JH + tl * 16 + lo;

    bf16x8 bfr[TILES][KT];
    #pragma unroll
    for (int tl = 0; tl < TILES; ++tl)
        #pragma unroll
        for (int kt = 0; kt < KT; ++kt) {
            const float* up = Umat + (size_t)(kt * 32 + hi * 8) * NGu + gc[tl];
            bf16x8 v;
            #pragma unroll
            for (int i = 0; i < 8; ++i) v[i] = (short)f2bf(up[(size_t)i * NGu]);
            bfr[tl][kt] = v;
        }

    float creg[TILES][4];
    #pragma unroll
    for (int tl = 0; tl < TILES; ++tl)
        #pragma unroll
        for (int r = 0; r < 4; ++r) creg[tl][r] = 0.f;

    for (int t = 0; t < SEQT; ++t) {
        if (w == 0) {
            if (t > 0) {   // critical: own-group h flags
                int guard = 0; bool ok;
                do {
                    bool pred = true;
                    if (lane < 2 * WPG)
                        pred = ((int)ald(&Fown[(grp * 2 * WPG + lane) * 16]) >= t);
                    ok = __all(pred);
                    if (!ok) __builtin_amdgcn_s_sleep(1);
                } while (!ok && ++guard < LIM);
            }
            {   // non-critical: xg ready + ring guard (throttled)
                int guard = 0; bool ok;
                do {
                    bool pred = true;
                    if (XATOMIC && lane < 4) {
                        const int mt = (lane * U_ + J) >> xmsh;
                        const int fi = mt * xph + (t & (xph - 1));
                        pred = ((int)ald(&Xown[fi * 16]) >= t + 1);
                    }
                    for (int i = lane; i < nGd; i += 64)
                        pred = pred && ((int)ald(&Xguard[i * 16]) >= t - (RING - 1));
                    ok = __all(pred);
                    if (!ok) __builtin_amdgcn_s_sleep(8);
                } while (!ok && ++guard < LIM);
            }
        }
        __syncthreads();   // B1: deps satisfied

        // xg load (bf16 slab t)
        u16x4 xr[TILES];
        const size_t xb = (size_t)((t & xmask) * 8 + grp) * NGu;
        #pragma unroll
        for (int tl = 0; tl < TILES; ++tl) {
            if (XATOMIC) xr[tl] = ldG8(xgring + (xb + gc[tl]) * 16 + hi * 4);
            else         xr[tl] = *(const u16x4*)(xgring + (xb + gc[tl]) * 16 + hi * 4);
        }

        if (t > 0) {
            const ushortT* hsrc = hring + (size_t)((t - 1) & (RING - 1)) * S;
            for (int i = tid; i < 16 * GR; i += 512) {
                const int row = i / GR, gi = i - row * GR;
                const int gs = gi ^ (row & 7);
                *(u16x8*)&hstage[(row * GR + gs) * 8] =
                    ldG16(hsrc + (size_t)(b0 + row) * U_ + gi * 8);
            }
        }
        __syncthreads();   // B2: h staged

        f32x4 acc[TILES];
        #pragma unroll
        for (int tl = 0; tl < TILES; ++tl) acc[tl] = f32x4{0.f, 0.f, 0.f, 0.f};
        if (t > 0) {
            #pragma unroll
            for (int kt = 0; kt < KT; ++kt) {
                const int gs = (kt * 4 + hi) ^ (lo & 7);
                const bf16x8 a = *(const bf16x8*)&hstage[(lo * GR + gs) * 8];
                #pragma unroll
                for (int tl = 0; tl < TILES; ++tl)
                    acc[tl] = __builtin_amdgcn_mfma_f32_16x16x32_bf16(a, bfr[tl][kt], acc[tl], 0, 0, 0);
            }
        }

        float p[TILES][4];
        #pragma unroll
        for (int tl = 0; tl < TILES; ++tl)
            #pragma unroll
            for (int r = 0; r < 4; ++r)
                p[tl][r] = acc[tl][r] + bf2f(xr[tl][r]);

        if (g4 != 2) {
            const int slot = (g4 == 3) ? 2 : g4;    // i->0, f->1, o->2
            #pragma unroll
            for (int tl = 0; tl < TILES; ++tl)
                #pragma unroll
                for (int r = 0; r < 4; ++r)
                    ex[((slot * 2 + chh) * JH + tl * 16 + lo) * 17 + hi * 4 + r] = sigmoidf_(p[tl][r]);
        }
        __syncthreads();   // B3: gates exchanged

        if (g4 == 2) {
            ushortT* hwr = hring + (size_t)(t & (RING - 1)) * S;
            #pragma unroll
            for (int tl = 0; tl < TILES; ++tl) {
                const int jh = tl * 16 + lo;
                const int j  = gc[tl] - 2 * U_;
                unsigned own[4], oth[4];
                #pragma unroll
                for (int r = 0; r < 4; ++r) {
                    const int row = hi * 4 + r;
                    const float i_ = ex[((0 * 2 + chh) * JH + jh) * 17 + row];
                    const float f_ = ex[((1 * 2 + chh) * JH + jh) * 17 + row];
                    const float o_ = ex[((2 * 2 + chh) * JH + jh) * 17 + row];
                    creg[tl][r] = f_ * creg[tl][r] + i_ * fmaxf(p[tl][r], 0.f);
                    const float hn = o_ * fmaxf(creg[tl][r], 0.f);
                    own[r] = (unsigned)f2bf(hn);
                }
                #pragma unroll
                for (int r = 0; r < 4; ++r)
                    oth[r] = (unsigned)__shfl_xor((int)own[r], 1);
                const int odd = lo & 1;
                const int rb = odd ? 2 : 0;
                const int je = j - odd;
                #pragma unroll
                for (int q = 0; q < 2; ++q) {
                    const int r = rb + q;
                    const unsigned pk = odd ? (oth[r] | (own[r] << 16))
                                            : (own[r] | (oth[r] << 16));
                    ast((unsigned*)&hwr[(size_t)(b0 + hi * 4 + r) * U_ + je], pk);
                }
            }
            asm volatile("s_waitcnt vmcnt(0)" ::: "memory");
            if (lane == 0)
                ast(&Fown[((grp * WPG + wgj) * 2 + chh) * 16], (unsigned)(t + 1));
        }
    }
}

// ---------------------------------------------------------------------------
// GEMM worker (flushless, P-phase): MC m-cols, W tile LDS-resident (staged
// once), h slab read via u64 LLC atomics with double-buffered k-pipeline,
// packed u32 xg stores. Throttled polls (s_sleep 32) — P steps of slack.
// ---------------------------------------------------------------------------
template<int MC, int NGATES, int KP, int P>
__device__ void worker_role(
    int mtile, int phase,
    const ushortT* __restrict__ WT,     // [NGATES][KP] bf16
    const float* __restrict__ bias,
    const ushortT* __restrict__ hring,  // [RING][128][KP]
    ushortT* __restrict__ xgring,       // [RING][8][NGATES][16]
    unsigned* Fup, int nUp,
    unsigned* Fguard, int nGd,
    unsigned* Xrel,
    char* smem)
{
    constexpr int GR2 = KP / 8;
    constexpr int NIT = KP / 32;
    constexpr int WR  = MC / 8;          // m-cols per wave
    constexpr int MT  = WR / 16;         // 16-col m-tiles per wave
    ushortT* Wl = (ushortT*)smem;                   // [MC][KP] swizzled granules
    ushortT* Xl = (ushortT*)(smem + (size_t)MC * KP * 2);   // 2 x [128][32]

    const int tid = threadIdx.x, w = tid >> 6, lane = tid & 63;
    const int lo = lane & 15, hi = lane >> 4;
    const int m0 = mtile * MC;
    const int row = tid >> 2, gq = tid & 3;
    const int gsx = gq ^ ((row >> 1) & 3);

    // stage W tile once
    for (int i = tid; i < MC * GR2; i += 512) {
        const int r_ = i / GR2, gi = i - r_ * GR2;
        const int gs = gi ^ (r_ & 7);
        *(u16x8*)&Wl[(r_ * GR2 + gs) * 8] =
            *(const u16x8*)(WT + (size_t)(m0 + r_) * KP + gi * 8);
    }
    float bv[MT][4];
    #pragma unroll
    for (int mt = 0; mt < MT; ++mt)
        #pragma unroll
        for (int j = 0; j < 4; ++j)
            bv[mt][j] = bias[m0 + w * WR + mt * 16 + hi * 4 + j];
    __syncthreads();

    for (int t = phase; t < SEQT; t += P) {
        if (w == 0) {
            int guard = 0; bool ok;
            do {
                bool pred = true;
                for (int i = lane; i < nUp; i += 64)
                    pred = pred && ((int)ald(&Fup[i * 16]) >= t + 1);
                for (int i = lane; i < nGd; i += 64)
                    pred = pred && ((int)ald(&Fguard[i * 16]) >= t - (RING - 1));
                ok = __all(pred);
                if (!ok) __builtin_amdgcn_s_sleep(32);
            } while (!ok && ++guard < LIM);
        }
        __syncthreads();

        const ushortT* hslab = hring + (size_t)(t & (RING - 1)) * 128 * KP;

        f32x4 acc[MT][8];
        #pragma unroll
        for (int mt = 0; mt < MT; ++mt)
            #pragma unroll
            for (int nn = 0; nn < 8; ++nn) acc[mt][nn] = f32x4{0.f, 0.f, 0.f, 0.f};

        u16x8 R = ldG16(hslab + (size_t)row * KP + gq * 8);
        for (int it = 0; it < NIT; ++it) {
            ushortT* Xc = Xl + (it & 1) * (128 * 32);
            *(u16x8*)&Xc[row * 32 + gsx * 8] = R;
            if (it + 1 < NIT)
                R = ldG16(hslab + (size_t)row * KP + (it + 1) * 32 + gq * 8);
            __syncthreads();
            const int k0 = it * 32;
            #pragma unroll
            for (int mt = 0; mt < MT; ++mt) {
                const int arow = w * WR + mt * 16 + lo;
                const int gsa = ((k0 >> 3) + hi) ^ (arow & 7);
                const bf16x8 a = *(const bf16x8*)&Wl[(arow * GR2 + gsa) * 8];
                #pragma unroll
                for (int nn = 0; nn < 8; ++nn) {
                    const int brow = nn * 16 + lo;
                    const bf16x8 b = *(const bf16x8*)&Xc[brow * 32 + (hi ^ ((brow >> 1) & 3)) * 8];
                    acc[mt][nn] = __builtin_amdgcn_mfma_f32_16x16x32_bf16(a, b, acc[mt][nn], 0, 0, 0);
                }
            }
        }

        // packed epilogue: adjacent-b pairs -> u32 atomic stores
        const size_t slab = (size_t)(t & (RING - 1)) * 8;
        #pragma unroll
        for (int mt = 0; mt < MT; ++mt) {
            #pragma unroll
            for (int nn = 0; nn < 8; ++nn) {
                const int b = nn * 16 + lo;
                unsigned own[4], oth[4];
                #pragma unroll
                for (int j = 0; j < 4; ++j)
                    own[j] = (unsigned)f2bf(acc[mt][nn][j] + bv[mt][j]);
                #pragma unroll
                for (int j = 0; j < 4; ++j)
                    oth[j] = (unsigned)__shfl_xor((int)own[j], 1);
                const int odd = lo & 1;
                const int jb = odd ? 2 : 0;
                const int be = (b & 15) - odd;
                #pragma unroll
                for (int q = 0; q < 2; ++q) {
                    const int j = jb + q;
                    const int m = m0 + w * WR + mt * 16 + hi * 4 + j;
                    const unsigned pk = odd ? (oth[j] | (own[j] << 16))
                                            : (own[j] | (oth[j] << 16));
                    ast((unsigned*)&xgring[((slab + nn) * NGATES + m) * 16 + be], pk);
                }
            }
        }
        asm volatile("s_waitcnt vmcnt(0)" ::: "memory");
        __syncthreads();
        if (tid == 0)
            ast(Xrel, (unsigned)(t + 1));
    }
}

// ---------------------------------------------------------------------------
// Megakernel. Grid 192 x 512 thr, 1 WG/CU.
//  [0,16) L0  [16,80) L1  [80,96) L2  [96,160) G1 (8mt x 8ph)  [160,192) G2 (8mt x 4ph)
// ---------------------------------------------------------------------------
struct MegaArgs {
    const float *U0, *U1, *U2;
    const ushortT *W1T, *W2T;
    const float *b1, *b2;
    const ushortT* xg0;
    ushortT *xg1, *xg2;
    ushortT *h0r, *h1r, *h2r;
    unsigned *F0, *F1, *F2, *X1, *X2;
};

__global__ __launch_bounds__(512, 1) void mega(MegaArgs A)
{
    extern __shared__ char smem[];
    const int bid = blockIdx.x;
    if (bid < 16) {
        rec_role<NU0, 128, false>(bid, A.U0, A.xg0, 511, A.h0r, A.F0,
                                  nullptr, 1, 0, A.X1, 64, smem);
    } else if (bid < 80) {
        rec_role<NU1, 64, true>(bid - 16, A.U1, A.xg1, RING - 1, A.h1r, A.F1,
                                A.X1, 8, 8, A.X2, 32, smem);
    } else if (bid < 96) {
        rec_role<NU2, 128, true>(bid - 80, A.U2, A.xg2, RING - 1, A.h2r, A.F2,
                                 A.X2, 4, 7, nullptr, 0, smem);
    } else if (bid < 160) {
        const int wid = bid - 96;
        const int mt = wid & 7, ph = wid >> 3;     // 8 mtiles x 8 phases
        worker_role<256, 2048, 256, 8>(mt, ph, A.W1T, A.b1, A.h0r, A.xg1,
                                       A.F0, 32, A.F1, 128, A.X1 + (mt * 8 + ph) * 16, smem);
    } else {
        const int wid = bid - 160;
        const int mt = wid & 7, ph = wid >> 3;     // 8 mtiles x 4 phases
        worker_role<128, 1024, 512, 4>(mt, ph, A.W2T, A.b2, A.h1r, A.xg2,
                                       A.F1, 128, A.F2, 32, A.X2 + (mt * 4 + ph) * 16, smem);
    }
}

// ---------------------------------------------------------------------------
// Head
// ---------------------------------------------------------------------------
__global__ __launch_bounds__(64) void head_kernel(
    const ushortT* __restrict__ h2,
    const float* __restrict__ Wd,
    const float* __restrict__ bd,
    const float* __restrict__ Wc,
    const float* __restrict__ bc,
    float* __restrict__ out)
{
    const int b = blockIdx.x;
    const int j = threadIdx.x;
    float a = bd[j];
    const ushortT* hrow = h2 + (size_t)b * NU2;
    #pragma unroll 4
    for (int k = 0; k < NU2; ++k)
        a += bf2f(hrow[k]) * Wd[(size_t)k * NDENSE + j];
    a = fmaxf(a, 0.f) * Wc[j];
    #pragma unroll
    for (int off = 32; off > 0; off >>= 1)
        a += __shfl_down(a, off);
    if (j == 0)
        out[b] = 1.f / (1.f + expf(-(a + bc[0])));
}

// ---------------------------------------------------------------------------
extern "C" void kernel_launch(void* const* d_in, const int* in_sizes, int n_in,
                              void* d_out, int out_size, void* d_ws, size_t ws_size,
                              hipStream_t stream)
{
    const int*   tokens = (const int*)  d_in[0];
    const float* emb    = (const float*)d_in[1];
    const float* W0     = (const float*)d_in[2];
    const float* Ur0    = (const float*)d_in[3];
    const float* b0v    = (const float*)d_in[4];
    const float* W1     = (const float*)d_in[5];
    const float* Ur1    = (const float*)d_in[6];
    const float* b1v    = (const float*)d_in[7];
    const float* W2     = (const float*)d_in[8];
    const float* Ur2    = (const float*)d_in[9];
    const float* b2v    = (const float*)d_in[10];
    const float* Wd     = (const float*)d_in[11];
    const float* bd     = (const float*)d_in[12];
    const float* Wc     = (const float*)d_in[13];
    const float* bc     = (const float*)d_in[14];
    float* out = (float*)d_out;

    char* p = (char*)d_ws;
    auto alloc = [&](size_t bytes) -> char* {
        char* q = p; p += (bytes + 255) & ~(size_t)255; return q;
    };
    ushortT* xg0   = (ushortT*)alloc((size_t)SEQT * 8 * 1024 * 16 * 2);  // 128 MB
    ushortT* xg1   = (ushortT*)alloc((size_t)RING * 8 * 2048 * 16 * 2);  // 16 MB
    ushortT* xg2   = (ushortT*)alloc((size_t)RING * 8 * 1024 * 16 * 2);  // 8 MB
    ushortT* h0r   = (ushortT*)alloc((size_t)RING * 128 * NU0 * 2);      // 2 MB
    ushortT* h1r   = (ushortT*)alloc((size_t)RING * 128 * NU1 * 2);      // 4 MB
    ushortT* h2r   = (ushortT*)alloc((size_t)RING * 128 * NU2 * 2);      // 2 MB
    ushortT* W0T   = (ushortT*)alloc((size_t)1024 * KP0 * 2);
    ushortT* W1T   = (ushortT*)alloc((size_t)2048 * NU0 * 2);
    ushortT* W2T   = (ushortT*)alloc((size_t)1024 * NU1 * 2);
    ushortT* embbf = (ushortT*)alloc((size_t)VOCABN * KP0 * 2);
    unsigned* flg  = (unsigned*)alloc(32768);

    // flag partition (16-word stride)
    unsigned* F0 = flg;             // 32  (16 L0 WGs x 2 c-waves)
    unsigned* F1 = F0 + 32 * 16;    // 128 (64 L1 WGs x 2)
    unsigned* F2 = F1 + 128 * 16;   // 32  (16 L2 WGs x 2)
    unsigned* X1 = F2 + 32 * 16;    // 64  (8 G1 mtiles x 8 phases)
    unsigned* X2 = X1 + 64 * 16;    // 32  (8 G2 mtiles x 4 phases)

    hipMemsetAsync(flg, 0, 32768, stream);

    convert_WT<<<512, 256, 0, stream>>>(W0, W0T, EMB_D, 1024, KP0, 1024 * KP0);
    convert_WT<<<512, 256, 0, stream>>>(W1, W1T, NU0, 2048, NU0, 2048 * NU0);
    convert_WT<<<512, 256, 0, stream>>>(W2, W2T, NU1, 1024, NU1, 1024 * NU1);
    convert_emb<<<1024, 256, 0, stream>>>(emb, embbf);

    gemm_xg0<<<dim3(SEQT, 8), 256, 0, stream>>>(embbf, tokens, W0T, b0v, xg0);

    MegaArgs A;
    A.U0 = Ur0; A.U1 = Ur1; A.U2 = Ur2;
    A.W1T = W1T; A.W2T = W2T;
    A.b1 = b1v; A.b2 = b2v;
    A.xg0 = xg0; A.xg1 = xg1; A.xg2 = xg2;
    A.h0r = h0r; A.h1r = h1r; A.h2r = h2r;
    A.F0 = F0; A.F1 = F1; A.F2 = F2; A.X1 = X1; A.X2 = X2;

    void* args[] = {&A};
    // smem: worker = MC*KP*2 (131072) + 2*128*32*2 (16384) = 147456 (max role)
    hipLaunchCooperativeKernel((void*)mega, dim3(192), dim3(512), args, 147456, stream);

    // final h of layer 2 = ring slab (511 & 31) = 31
    head_kernel<<<BATCH, 64, 0, stream>>>(h2r + (size_t)31 * 128 * NU2,
                                          Wd, bd, Wc, bc, out);
}